// Round 9
// baseline (268.387 us; speedup 1.0000x reference)
//
#include <hip/hip_runtime.h>

// GCN: H2 = relu(A @ relu(A@H @ W1 + b1) @ W2 + b2)
// A: COO (row,col,vals), E=1.6M, N=100k, feats 64 -> 128 -> 128.
// R11: SpMM dwordx4 gathers + 4-deep edge pipeline.
// R12/R13 (REVERTED): write-amplification lessons (see journal).
// R14: partition 256 blocks x 1024 thr; bucket_csr 1024 thr.
// R15/16: fused spmm+gemm per layer (WIN 281->272).
// R17/18: fused128 256-thr/32-row blocks + meta prefetch (WIN 272->264).
//      fused128 59us @ 33% occ, VALUBusy 24%, MfmaUtil 2% -> waves stall
//      on gather latency; MLP-per-wave limited (4 lines in flight).
// R19: 8-deep gather pipeline (8 outstanding lines/lane, ~2x MLP;
//      VGPR ~64->~100, still >=5 waves/SIMD). 4-deep + scalar tails.

#define NFEAT 64
#define NHID 128
#define BSHIFT 9              // 512 rows per bucket
#define BROWS (1 << BSHIFT)
#define NB_MAX 256            // supports n_nodes <= 131072 (17-bit col pack)

typedef __attribute__((ext_vector_type(8))) short bf16x8;
typedef __attribute__((ext_vector_type(4))) float f32x4;
typedef __attribute__((ext_vector_type(2))) float f32x2;

// ---------------- bf16 helpers ----------------
__device__ __forceinline__ unsigned short f2bf(float x) {
  unsigned u = __float_as_uint(x);
  unsigned r = (u + 0x7FFFu + ((u >> 16) & 1u)) >> 16;  // RNE
  return (unsigned short)r;
}
__device__ __forceinline__ unsigned pack2(float a, float b) {
  return (unsigned)f2bf(a) | ((unsigned)f2bf(b) << 16);
}

// ---------------- fp8 e4m3 helpers (HW cvt) ----------------
__device__ __forceinline__ unsigned pk_fp8x4(float a, float b, float c, float d) {
  int w = __builtin_amdgcn_cvt_pk_fp8_f32(a, b, 0, false);   // bytes 0,1
  w = __builtin_amdgcn_cvt_pk_fp8_f32(c, d, w, true);        // bytes 2,3
  return (unsigned)w;
}
__device__ __forceinline__ unsigned char f2fp8(float x) {
  return (unsigned char)(__builtin_amdgcn_cvt_pk_fp8_f32(x, 0.f, 0, false) & 0xFF);
}

// accumulate 16 fp8 (one uint4) scaled by v into 8 packed-f32 accumulators
__device__ __forceinline__ void acc16(f32x2* a, uint4 q, float v) {
  f32x2 vv = {v, v};
  a[0] += vv * __builtin_amdgcn_cvt_pk_f32_fp8(q.x, false);
  a[1] += vv * __builtin_amdgcn_cvt_pk_f32_fp8(q.x, true);
  a[2] += vv * __builtin_amdgcn_cvt_pk_f32_fp8(q.y, false);
  a[3] += vv * __builtin_amdgcn_cvt_pk_f32_fp8(q.y, true);
  a[4] += vv * __builtin_amdgcn_cvt_pk_f32_fp8(q.z, false);
  a[5] += vv * __builtin_amdgcn_cvt_pk_f32_fp8(q.z, true);
  a[6] += vv * __builtin_amdgcn_cvt_pk_f32_fp8(q.w, false);
  a[7] += vv * __builtin_amdgcn_cvt_pk_f32_fp8(q.w, true);
}

// gather one row's features: RS uint4 per source row, lane owns chunk f.
// R19: 8-deep pipeline (8 outstanding gather lines + meta prefetched one
// 8-batch ahead); 4-deep and scalar tails. Accumulation order == seq-j.
template <int RS>
__device__ __forceinline__ void gather_row(
    const int2* __restrict__ sedge, const uint4* __restrict__ Hq,
    int beg, int end, int f, f32x2* a) {
  int j = beg;
  if ((j & 1) && j < end) {  // peel to 16B-align the meta stream
    int2 ev = sedge[j];
    acc16(a, Hq[ev.x * RS + f], __int_as_float(ev.y));
    ++j;
  }
  const int4* mp = (const int4*)sedge;
  if (j + 8 <= end) {
    int4 m0 = mp[(j >> 1) + 0], m1 = mp[(j >> 1) + 1];
    int4 m2 = mp[(j >> 1) + 2], m3 = mp[(j >> 1) + 3];
    while (j + 16 <= end) {
      uint4 q0 = Hq[m0.x * RS + f], q1 = Hq[m0.z * RS + f];
      uint4 q2 = Hq[m1.x * RS + f], q3 = Hq[m1.z * RS + f];
      uint4 q4 = Hq[m2.x * RS + f], q5 = Hq[m2.z * RS + f];
      uint4 q6 = Hq[m3.x * RS + f], q7 = Hq[m3.z * RS + f];
      int4 n0 = mp[(j >> 1) + 4], n1 = mp[(j >> 1) + 5];  // prefetch meta
      int4 n2 = mp[(j >> 1) + 6], n3 = mp[(j >> 1) + 7];
      acc16(a, q0, __int_as_float(m0.y));
      acc16(a, q1, __int_as_float(m0.w));
      acc16(a, q2, __int_as_float(m1.y));
      acc16(a, q3, __int_as_float(m1.w));
      acc16(a, q4, __int_as_float(m2.y));
      acc16(a, q5, __int_as_float(m2.w));
      acc16(a, q6, __int_as_float(m3.y));
      acc16(a, q7, __int_as_float(m3.w));
      m0 = n0; m1 = n1; m2 = n2; m3 = n3;
      j += 8;
    }
    uint4 q0 = Hq[m0.x * RS + f], q1 = Hq[m0.z * RS + f];
    uint4 q2 = Hq[m1.x * RS + f], q3 = Hq[m1.z * RS + f];
    uint4 q4 = Hq[m2.x * RS + f], q5 = Hq[m2.z * RS + f];
    uint4 q6 = Hq[m3.x * RS + f], q7 = Hq[m3.z * RS + f];
    acc16(a, q0, __int_as_float(m0.y));
    acc16(a, q1, __int_as_float(m0.w));
    acc16(a, q2, __int_as_float(m1.y));
    acc16(a, q3, __int_as_float(m1.w));
    acc16(a, q4, __int_as_float(m2.y));
    acc16(a, q5, __int_as_float(m2.w));
    acc16(a, q6, __int_as_float(m3.y));
    acc16(a, q7, __int_as_float(m3.w));
    j += 8;
  }
  if (j + 4 <= end) {
    int4 m0 = mp[j >> 1], m1 = mp[(j >> 1) + 1];
    uint4 q0 = Hq[m0.x * RS + f], q1 = Hq[m0.z * RS + f];
    uint4 q2 = Hq[m1.x * RS + f], q3 = Hq[m1.z * RS + f];
    acc16(a, q0, __int_as_float(m0.y));
    acc16(a, q1, __int_as_float(m0.w));
    acc16(a, q2, __int_as_float(m1.y));
    acc16(a, q3, __int_as_float(m1.w));
    j += 4;
  }
  for (; j < end; ++j) {
    int2 ev = sedge[j];
    acc16(a, Hq[ev.x * RS + f], __int_as_float(ev.y));
  }
}

// ---------------- fused prep: H->fp8, W1/W2 -> swizzled bf16 ----------------
__global__ __launch_bounds__(256) void prep_kernel(
    const float* __restrict__ H, const float* __restrict__ W1,
    const float* __restrict__ W2, unsigned char* __restrict__ Hf8,
    unsigned short* __restrict__ Wsw1, unsigned short* __restrict__ Wsw2,
    int n8) {
  const int total = n8 + 64 * 128 + 128 * 128;
  for (int w = blockIdx.x * 256 + threadIdx.x; w < total; w += gridDim.x * 256) {
    if (w < n8) {
      float4 a = ((const float4*)H)[2 * w];
      float4 b = ((const float4*)H)[2 * w + 1];
      ((uint2*)Hf8)[w] = make_uint2(pk_fp8x4(a.x, a.y, a.z, a.w),
                                    pk_fp8x4(b.x, b.y, b.z, b.w));
    } else {
      int idx = w - n8;
      const float* W = W1;
      unsigned short* Wsw = Wsw1;
      if (idx >= 64 * 128) {
        idx -= 64 * 128;
        W = W2;
        Wsw = Wsw2;
      }
      int j = idx & 7, q = (idx >> 3) & 3, nn = (idx >> 5) & 127, kt = idx >> 12;
      int k = kt * 32 + q * 8 + j;
      Wsw[idx] = f2bf(W[(size_t)k * 128 + nn]);
    }
  }
}

// ---------------- bucket histogram (LDS-aggregated, int4 reads) ------------
__global__ __launch_bounds__(256) void bhist_kernel(
    const int* __restrict__ row, int* __restrict__ bcnt, int n_edges, int nb) {
  __shared__ int h[NB_MAX];
  for (int i = threadIdx.x; i < NB_MAX; i += 256) h[i] = 0;
  __syncthreads();
  const int n4 = n_edges >> 2;
  for (int i = blockIdx.x * 256 + threadIdx.x; i < n4; i += gridDim.x * 256) {
    int4 r4 = ((const int4*)row)[i];
    atomicAdd(&h[r4.x >> BSHIFT], 1);
    atomicAdd(&h[r4.y >> BSHIFT], 1);
    atomicAdd(&h[r4.z >> BSHIFT], 1);
    atomicAdd(&h[r4.w >> BSHIFT], 1);
  }
  if (blockIdx.x == 0 && threadIdx.x < (n_edges & 3))
    atomicAdd(&h[row[(n4 << 2) + threadIdx.x] >> BSHIFT], 1);
  __syncthreads();
  for (int i = threadIdx.x; i < nb; i += 256)
    if (h[i]) atomicAdd(&bcnt[i], h[i]);
}

// ---------------- bucket scan -> bbase[nb+1], cur[nb], row_ptr[n] -----------
__global__ __launch_bounds__(NB_MAX) void bscan_kernel(
    const int* __restrict__ bcnt, int* __restrict__ bbase, int* __restrict__ cur,
    int* __restrict__ row_ptr, int nb, int n) {
  __shared__ int sm[NB_MAX];
  int t = threadIdx.x;
  int v = (t < nb) ? bcnt[t] : 0;
  sm[t] = v;
  __syncthreads();
  for (int off = 1; off < NB_MAX; off <<= 1) {
    int u = (t >= off) ? sm[t - off] : 0;
    __syncthreads();
    sm[t] += u;
    __syncthreads();
  }
  if (t < nb) {
    bbase[t] = sm[t] - v;
    cur[t] = sm[t] - v;
  }
  if (t == nb - 1) {
    bbase[nb] = sm[t];
    row_ptr[n] = sm[t];
  }
}

// ---------------- pass A: multi-split partition into buckets ----------------
// 256 blocks (256B per-bucket chunks for write coalescing) x 1024 threads
// (16 waves/CU). Both edge passes int4/float4-vectorized.
__global__ __launch_bounds__(1024) void partition_kernel(
    const int* __restrict__ row, const int* __restrict__ col,
    const float* __restrict__ vals, int* __restrict__ cur,
    int2* __restrict__ bedge, int n_edges) {
  __shared__ int h[NB_MAX], base[NB_MAX], rk[NB_MAX];
  for (int i = threadIdx.x; i < NB_MAX; i += 1024) {
    h[i] = 0;
    rk[i] = 0;
  }
  __syncthreads();
  const int t0 = blockIdx.x * 1024 + threadIdx.x;
  const int T = gridDim.x * 1024;
  const int n4 = n_edges >> 2;
  for (int i = t0; i < n4; i += T) {
    int4 r4 = ((const int4*)row)[i];
    atomicAdd(&h[r4.x >> BSHIFT], 1);
    atomicAdd(&h[r4.y >> BSHIFT], 1);
    atomicAdd(&h[r4.z >> BSHIFT], 1);
    atomicAdd(&h[r4.w >> BSHIFT], 1);
  }
  if (blockIdx.x == 0 && threadIdx.x < (n_edges & 3))
    atomicAdd(&h[row[(n4 << 2) + threadIdx.x] >> BSHIFT], 1);
  __syncthreads();
  for (int i = threadIdx.x; i < NB_MAX; i += 1024)
    base[i] = h[i] ? atomicAdd(&cur[i], h[i]) : 0;
  __syncthreads();
  for (int i = t0; i < n4; i += T) {
    int4 r4 = ((const int4*)row)[i];
    int4 c4 = ((const int4*)col)[i];
    float4 v4 = ((const float4*)vals)[i];
    {
      int b = r4.x >> BSHIFT;
      int p = base[b] + atomicAdd(&rk[b], 1);
      bedge[p] = make_int2(((r4.x & (BROWS - 1)) << 17) | c4.x, __float_as_int(v4.x));
    }
    {
      int b = r4.y >> BSHIFT;
      int p = base[b] + atomicAdd(&rk[b], 1);
      bedge[p] = make_int2(((r4.y & (BROWS - 1)) << 17) | c4.y, __float_as_int(v4.y));
    }
    {
      int b = r4.z >> BSHIFT;
      int p = base[b] + atomicAdd(&rk[b], 1);
      bedge[p] = make_int2(((r4.z & (BROWS - 1)) << 17) | c4.z, __float_as_int(v4.z));
    }
    {
      int b = r4.w >> BSHIFT;
      int p = base[b] + atomicAdd(&rk[b], 1);
      bedge[p] = make_int2(((r4.w & (BROWS - 1)) << 17) | c4.w, __float_as_int(v4.w));
    }
  }
  if (blockIdx.x == 0 && threadIdx.x < (n_edges & 3)) {
    int e = (n4 << 2) + threadIdx.x;
    int r = row[e];
    int b = r >> BSHIFT;
    int p = base[b] + atomicAdd(&rk[b], 1);
    bedge[p] = make_int2(((r & (BROWS - 1)) << 17) | col[e], __float_as_int(vals[e]));
  }
}

// ---------------- pass B: per-bucket exact CSR (1024 thr) ----------------
__global__ __launch_bounds__(1024) void bucket_csr_kernel(
    const int* __restrict__ bbase, const int2* __restrict__ bedge,
    int* __restrict__ row_ptr, int2* __restrict__ sedge, int n) {
  __shared__ int cnt[BROWS];
  __shared__ int sm[BROWS];
  const int b = blockIdx.x;
  const int t = threadIdx.x;
  const int beg = bbase[b], end = bbase[b + 1];
  if (t < BROWS) cnt[t] = 0;
  __syncthreads();
  for (int j = beg + t; j < end; j += 1024)
    atomicAdd(&cnt[((unsigned)bedge[j].x) >> 17], 1);
  __syncthreads();
  int v = (t < BROWS) ? cnt[t] : 0;
  if (t < BROWS) sm[t] = v;
  __syncthreads();
  for (int off = 1; off < BROWS; off <<= 1) {
    int u = (t >= off && t < BROWS) ? sm[t - off] : 0;
    __syncthreads();
    if (t < BROWS) sm[t] += u;
    __syncthreads();
  }
  int incl = (t < BROWS) ? sm[t] : 0;
  __syncthreads();
  if (t < BROWS) {
    sm[t] = incl - v;  // exclusive local base
    int r = (b << BSHIFT) + t;
    if (r < n) row_ptr[r] = beg + sm[t];
    cnt[t] = 0;
  }
  __syncthreads();
  for (int j = beg + t; j < end; j += 1024) {
    int2 ev = bedge[j];
    int rl = ((unsigned)ev.x) >> 17;
    int rank = atomicAdd(&cnt[rl], 1);
    sedge[beg + sm[rl] + rank] = make_int2(ev.x & 0x1FFFF, ev.y);
  }
}

// ---------------- fused layer 1: H1f8 = fp8(relu((A@Hf8) @ W1 + b1)) -------
// 256 thr. Phase 1: 64 rows, 4 lanes/row gather 64-feat fp8 rows -> LDS bf16
// tile [64][144B]. Phase 2: 4 waves x 16 rows MFMA vs Wsw1.
__global__ __launch_bounds__(256) void fused64_kernel(
    const int* __restrict__ row_ptr, const int2* __restrict__ sedge,
    const unsigned char* __restrict__ Hf8,
    const unsigned short* __restrict__ Wsw,
    const float* __restrict__ b, unsigned char* __restrict__ H1f8, int n) {
  __shared__ uint4 tile[64 * 9];  // stride 9 uint4 = 144B
  const int tid = threadIdx.x;
  {
    const int rl = tid >> 2, f = tid & 3;
    const int r = blockIdx.x * 64 + rl;
    int beg = 0, end = 0;
    if (r < n) {
      beg = row_ptr[r];
      end = row_ptr[r + 1];
    }
    f32x2 a[8];
#pragma unroll
    for (int i = 0; i < 8; ++i) a[i] = (f32x2){0.f, 0.f};
    gather_row<4>(sedge, (const uint4*)Hf8, beg, end, f, a);
    tile[rl * 9 + f * 2] =
        make_uint4(pack2(a[0].x, a[0].y), pack2(a[1].x, a[1].y),
                   pack2(a[2].x, a[2].y), pack2(a[3].x, a[3].y));
    tile[rl * 9 + f * 2 + 1] =
        make_uint4(pack2(a[4].x, a[4].y), pack2(a[5].x, a[5].y),
                   pack2(a[6].x, a[6].y), pack2(a[7].x, a[7].y));
  }
  const int lane = tid & 63, wave = tid >> 6;
  const int m = lane & 15, quad = lane >> 4;
  bf16x8 bfr[2][8];
#pragma unroll
  for (int kt = 0; kt < 2; ++kt)
#pragma unroll
    for (int c = 0; c < 8; ++c)
      bfr[kt][c] = *(const bf16x8*)(Wsw + ((size_t)(kt * 128 + c * 16 + m)) * 32 + quad * 8);
  __syncthreads();
  f32x4 acc[8];
#pragma unroll
  for (int c = 0; c < 8; ++c) acc[c] = (f32x4){0.f, 0.f, 0.f, 0.f};
#pragma unroll
  for (int kt = 0; kt < 2; ++kt) {
    bf16x8 a = *(const bf16x8*)&tile[(wave * 16 + m) * 9 + kt * 4 + quad];
#pragma unroll
    for (int c = 0; c < 8; ++c)
      acc[c] = __builtin_amdgcn_mfma_f32_16x16x32_bf16(a, bfr[kt][c], acc[c], 0, 0, 0);
  }
  const int r0 = blockIdx.x * 64 + wave * 16;
#pragma unroll
  for (int c = 0; c < 8; ++c) {
    float bias = b[c * 16 + m];
#pragma unroll
    for (int i = 0; i < 4; ++i) {
      int rr = r0 + quad * 4 + i;
      if (rr >= n) continue;
      H1f8[(size_t)rr * 128 + c * 16 + m] = f2fp8(fmaxf(acc[c][i] + bias, 0.f));
    }
  }
}

// ---------------- fused layer 2: out = relu((A@H1f8) @ W2 + b2) ------------
// 256 thr, 32 rows/block. Phase 1: 8 lanes/row gather 128-feat fp8 rows ->
// LDS tile [32][272B]. Phase 2: 4 waves = 2 row-groups x 2 col-halves.
__global__ __launch_bounds__(256) void fused128_kernel(
    const int* __restrict__ row_ptr, const int2* __restrict__ sedge,
    const unsigned char* __restrict__ H1f8,
    const unsigned short* __restrict__ Wsw,
    const float* __restrict__ b, float* __restrict__ out, int n) {
  __shared__ uint4 tile[32 * 17];  // stride 17 uint4 = 272B
  const int tid = threadIdx.x;
  {
    const int rl = tid >> 3, f = tid & 7;
    const int r = blockIdx.x * 32 + rl;
    int beg = 0, end = 0;
    if (r < n) {
      beg = row_ptr[r];
      end = row_ptr[r + 1];
    }
    f32x2 a[8];
#pragma unroll
    for (int i = 0; i < 8; ++i) a[i] = (f32x2){0.f, 0.f};
    gather_row<8>(sedge, (const uint4*)H1f8, beg, end, f, a);
    tile[rl * 17 + f * 2] =
        make_uint4(pack2(a[0].x, a[0].y), pack2(a[1].x, a[1].y),
                   pack2(a[2].x, a[2].y), pack2(a[3].x, a[3].y));
    tile[rl * 17 + f * 2 + 1] =
        make_uint4(pack2(a[4].x, a[4].y), pack2(a[5].x, a[5].y),
                   pack2(a[6].x, a[6].y), pack2(a[7].x, a[7].y));
  }
  const int lane = tid & 63, wave = tid >> 6;
  const int m = lane & 15, quad = lane >> 4;
  const int g = wave >> 1, h = wave & 1;  // row group (16), col half (64)
  bf16x8 bfr[4][4];
#pragma unroll
  for (int kt = 0; kt < 4; ++kt)
#pragma unroll
    for (int c = 0; c < 4; ++c)
      bfr[kt][c] = *(const bf16x8*)(Wsw + ((size_t)(kt * 128 + (h * 4 + c) * 16 + m)) * 32 + quad * 8);
  __syncthreads();
  f32x4 acc[4];
#pragma unroll
  for (int c = 0; c < 4; ++c) acc[c] = (f32x4){0.f, 0.f, 0.f, 0.f};
#pragma unroll
  for (int kt = 0; kt < 4; ++kt) {
    bf16x8 a = *(const bf16x8*)&tile[(g * 16 + m) * 17 + kt * 4 + quad];
#pragma unroll
    for (int c = 0; c < 4; ++c)
      acc[c] = __builtin_amdgcn_mfma_f32_16x16x32_bf16(a, bfr[kt][c], acc[c], 0, 0, 0);
  }
  const int r0 = blockIdx.x * 32 + g * 16;
#pragma unroll
  for (int c = 0; c < 4; ++c) {
    float bias = b[(h * 4 + c) * 16 + m];
#pragma unroll
    for (int i = 0; i < 4; ++i) {
      int rr = r0 + quad * 4 + i;
      if (rr >= n) continue;
      out[(size_t)rr * 128 + (h * 4 + c) * 16 + m] = fmaxf(acc[c][i] + bias, 0.f);
    }
  }
}

// ---------------- fallback path (f32 atomics + f32 VALU GEMM) ----------------
__global__ __launch_bounds__(256) void spmm64_atomic(
    const int* __restrict__ row, const int* __restrict__ col,
    const float* __restrict__ vals, const float* __restrict__ Hin,
    float* __restrict__ out, int n_edges) {
  int tid = blockIdx.x * 256 + threadIdx.x;
  int e = tid >> 4, f = tid & 15;
  if (e >= n_edges) return;
  int c = col[e], r = row[e];
  float v = vals[e];
  float4 h = ((const float4*)Hin)[(size_t)c * 16 + f];
  float* o = out + (size_t)r * 64 + f * 4;
  atomicAdd(o + 0, v * h.x);
  atomicAdd(o + 1, v * h.y);
  atomicAdd(o + 2, v * h.z);
  atomicAdd(o + 3, v * h.w);
}

__global__ __launch_bounds__(256) void spmm128_atomic(
    const int* __restrict__ row, const int* __restrict__ col,
    const float* __restrict__ vals, const float* __restrict__ Hin,
    float* __restrict__ out, int n_edges) {
  int tid = blockIdx.x * 256 + threadIdx.x;
  int e = tid >> 5, f = tid & 31;
  if (e >= n_edges) return;
  int c = col[e], r = row[e];
  float v = vals[e];
  float4 h = ((const float4*)Hin)[(size_t)c * 32 + f];
  float* o = out + (size_t)r * 128 + f * 4;
  atomicAdd(o + 0, v * h.x);
  atomicAdd(o + 1, v * h.y);
  atomicAdd(o + 2, v * h.z);
  atomicAdd(o + 3, v * h.w);
}

template <int K>
__global__ __launch_bounds__(256) void gemm_tiled_relu(
    const float* __restrict__ A, const float* __restrict__ W,
    const float* __restrict__ b, float* __restrict__ out, int n) {
  constexpr int KB = 32;
  constexpr int RP = 132;
  __shared__ float As[KB][RP];
  __shared__ float Ws[KB][128];
  const int t = threadIdx.x;
  const int tx = t & 15, ty = t >> 4;
  const int r0 = blockIdx.x * 128;
  float4 acc0[8], acc1[8];
#pragma unroll
  for (int i = 0; i < 8; ++i) {
    acc0[i] = make_float4(0.f, 0.f, 0.f, 0.f);
    acc1[i] = make_float4(0.f, 0.f, 0.f, 0.f);
  }
  for (int k0 = 0; k0 < K; k0 += KB) {
#pragma unroll
    for (int q = 0; q < 4; ++q) {
      int f = q * 256 + t;
      int kk = f >> 5, cv = f & 31;
      ((float4*)&Ws[kk][0])[cv] = ((const float4*)(W + (size_t)(k0 + kk) * 128))[cv];
    }
#pragma unroll
    for (int q = 0; q < 4; ++q) {
      int f = q * 256 + t;
      int r = f >> 3, kv = f & 7;
      float4 av = make_float4(0.f, 0.f, 0.f, 0.f);
      if (r0 + r < n) av = ((const float4*)(A + (size_t)(r0 + r) * K + k0))[kv];
      As[4 * kv + 0][r] = av.x;
      As[4 * kv + 1][r] = av.y;
      As[4 * kv + 2][r] = av.z;
      As[4 * kv + 3][r] = av.w;
    }
    __syncthreads();
#pragma unroll
    for (int k = 0; k < KB; ++k) {
      float4 w0 = *((const float4*)&Ws[k][4 * tx]);
      float4 w1 = *((const float4*)&Ws[k][64 + 4 * tx]);
#pragma unroll
      for (int i = 0; i < 8; ++i) {
        float a = As[k][ty + 16 * i];
        acc0[i].x = fmaf(a, w0.x, acc0[i].x);
        acc0[i].y = fmaf(a, w0.y, acc0[i].y);
        acc0[i].z = fmaf(a, w0.z, acc0[i].z);
        acc0[i].w = fmaf(a, w0.w, acc0[i].w);
        acc1[i].x = fmaf(a, w1.x, acc1[i].x);
        acc1[i].y = fmaf(a, w1.y, acc1[i].y);
        acc1[i].z = fmaf(a, w1.z, acc1[i].z);
        acc1[i].w = fmaf(a, w1.w, acc1[i].w);
      }
    }
    __syncthreads();
  }
  float4 bb0 = ((const float4*)b)[tx];
  float4 bb1 = ((const float4*)(b + 64))[tx];
#pragma unroll
  for (int i = 0; i < 8; ++i) {
    int r = r0 + ty + 16 * i;
    if (r >= n) continue;
    float4 o0, o1;
    o0.x = fmaxf(acc0[i].x + bb0.x, 0.f);
    o0.y = fmaxf(acc0[i].y + bb0.y, 0.f);
    o0.z = fmaxf(acc0[i].z + bb0.z, 0.f);
    o0.w = fmaxf(acc0[i].w + bb0.w, 0.f);
    o1.x = fmaxf(acc1[i].x + bb1.x, 0.f);
    o1.y = fmaxf(acc1[i].y + bb1.y, 0.f);
    o1.z = fmaxf(acc1[i].z + bb1.z, 0.f);
    o1.w = fmaxf(acc1[i].w + bb1.w, 0.f);
    ((float4*)(out + (size_t)r * 128))[tx] = o0;
    ((float4*)(out + (size_t)r * 128 + 64))[tx] = o1;
  }
}

extern "C" void kernel_launch(void* const* d_in, const int* in_sizes, int n_in,
                              void* d_out, int out_size, void* d_ws, size_t ws_size,
                              hipStream_t stream) {
  const int* row = (const int*)d_in[0];
  const int* col = (const int*)d_in[1];
  const float* vals = (const float*)d_in[2];
  const float* H = (const float*)d_in[3];
  const float* W1 = (const float*)d_in[4];
  const float* b1 = (const float*)d_in[5];
  const float* W2 = (const float*)d_in[6];
  const float* b2 = (const float*)d_in[7];
  float* out = (float*)d_out;

  const int n_edges = in_sizes[0];
  const int n_nodes = in_sizes[3] / NFEAT;
  const int nb = (n_nodes + BROWS - 1) / BROWS;

  // Workspace layout (CSR path):
  // bedge E*8 | Hf8 N*64 | H1f8 N*128 | sedge E*8
  // | Wsw1 | Wsw2 | bcnt | bbase | cur | row_ptr
  size_t off = 0;
  char* base = (char*)d_ws;
  int2* bedge = (int2*)(base + off);  off += (size_t)n_edges * 8;
  unsigned char* Hf8 = (unsigned char*)(base + off);   off += (size_t)n_nodes * NFEAT;
  unsigned char* H1f8 = (unsigned char*)(base + off);  off += (size_t)n_nodes * NHID;
  int2* sedge = (int2*)(base + off);  off += (size_t)n_edges * 8;
  unsigned short* Wsw1 = (unsigned short*)(base + off); off += 64 * 128 * 2;
  unsigned short* Wsw2 = (unsigned short*)(base + off); off += 128 * 128 * 2;
  int* bcnt = (int*)(base + off);     off += NB_MAX * 4;
  int* bbase = (int*)(base + off);    off += (NB_MAX + 1) * 4;
  int* cur = (int*)(base + off);      off += NB_MAX * 4;
  int* row_ptr = (int*)(base + off);  off += ((size_t)n_nodes + 1) * 4;
  const size_t needed = off;

  if (ws_size >= needed && nb <= NB_MAX && n_nodes <= (1 << 17)) {
    // ---- bucket-sort CSR build ----
    hipMemsetAsync(bcnt, 0, NB_MAX * sizeof(int), stream);
    bhist_kernel<<<1024, 256, 0, stream>>>(row, bcnt, n_edges, nb);
    bscan_kernel<<<1, NB_MAX, 0, stream>>>(bcnt, bbase, cur, row_ptr, nb, n_nodes);
    partition_kernel<<<256, 1024, 0, stream>>>(row, col, vals, cur, bedge, n_edges);
    bucket_csr_kernel<<<nb, 1024, 0, stream>>>(bbase, bedge, row_ptr, sedge, n_nodes);

    // Fused prep: H -> fp8, W1/W2 -> swizzled bf16.
    prep_kernel<<<1024, 256, 0, stream>>>(H, W1, W2, Hf8, Wsw1, Wsw2,
                                          n_nodes * NFEAT / 8);

    // Layer 1 fused: H1f8 = fp8(relu((A@Hf8) @ W1 + b1))
    fused64_kernel<<<(n_nodes + 63) / 64, 256, 0, stream>>>(
        row_ptr, sedge, Hf8, Wsw1, b1, H1f8, n_nodes);
    // Layer 2 fused: out = relu((A@H1f8) @ W2 + b2)
    fused128_kernel<<<(n_nodes + 31) / 32, 256, 0, stream>>>(
        row_ptr, sedge, H1f8, Wsw2, b2, out, n_nodes);
  } else {
    // ---- fallback: atomic scatter path (all f32) ----
    float* fAH = (float*)d_ws;
    float* fH1 = fAH + (size_t)n_nodes * NFEAT;
    hipMemsetAsync(fAH, 0, (size_t)n_nodes * NFEAT * sizeof(float), stream);
    hipMemsetAsync(out, 0, (size_t)n_nodes * NHID * sizeof(float), stream);
    spmm64_atomic<<<(n_edges * 16 + 255) / 256, 256, 0, stream>>>(row, col, vals, H, fAH, n_edges);
    gemm_tiled_relu<64><<<(n_nodes + 127) / 128, 256, 0, stream>>>(fAH, W1, b1, fH1, n_nodes);
    spmm128_atomic<<<(n_edges * 32 + 255) / 256, 256, 0, stream>>>(row, col, vals, fH1, out, n_edges);
    gemm_tiled_relu<128><<<(n_nodes + 127) / 128, 256, 0, stream>>>(out, W2, b2, out, n_nodes);
  }
}

// Round 11
// 261.413 us; speedup vs baseline: 1.0267x; 1.0267x over previous
//
#include <hip/hip_runtime.h>

// GCN: H2 = relu(A @ relu(A@H @ W1 + b1) @ W2 + b2)
// A: COO (row,col,vals), E=1.6M, N=100k, feats 64 -> 128 -> 128.
// R11: SpMM dwordx4 gathers + 4-deep edge pipeline.
// R12/R13 (REVERTED): write-amplification lessons (see journal).
// R14: partition 256 blocks x 1024 thr; bucket_csr 1024 thr.
// R15/16: fused spmm+gemm per layer (WIN 281->272).
// R17/18: fused128 256-thr/32-row blocks + meta prefetch (WIN 272->264).
// R19 (REVERTED): 8-deep gather pipeline -> occupancy 33->26%, fused128
//      59->65us. Per-wave depth beyond 4 loses more residency than it
//      gains MLP.
// R20: revert to 4-deep gather; halve blocks again (confirmed lever,
//      R15->R17 was -5.4us): fused128 128-thr/16-row blocks (2 waves,
//      g=0, h=wave), fused64 128-thr/32-row blocks. Finer scheduling
//      granularity + smaller barrier-coupling set.
// R21: resubmit of R20 (GPUAcquisitionTimeout, no measurement taken).

#define NFEAT 64
#define NHID 128
#define BSHIFT 9              // 512 rows per bucket
#define BROWS (1 << BSHIFT)
#define NB_MAX 256            // supports n_nodes <= 131072 (17-bit col pack)

typedef __attribute__((ext_vector_type(8))) short bf16x8;
typedef __attribute__((ext_vector_type(4))) float f32x4;
typedef __attribute__((ext_vector_type(2))) float f32x2;

// ---------------- bf16 helpers ----------------
__device__ __forceinline__ unsigned short f2bf(float x) {
  unsigned u = __float_as_uint(x);
  unsigned r = (u + 0x7FFFu + ((u >> 16) & 1u)) >> 16;  // RNE
  return (unsigned short)r;
}
__device__ __forceinline__ unsigned pack2(float a, float b) {
  return (unsigned)f2bf(a) | ((unsigned)f2bf(b) << 16);
}

// ---------------- fp8 e4m3 helpers (HW cvt) ----------------
__device__ __forceinline__ unsigned pk_fp8x4(float a, float b, float c, float d) {
  int w = __builtin_amdgcn_cvt_pk_fp8_f32(a, b, 0, false);   // bytes 0,1
  w = __builtin_amdgcn_cvt_pk_fp8_f32(c, d, w, true);        // bytes 2,3
  return (unsigned)w;
}
__device__ __forceinline__ unsigned char f2fp8(float x) {
  return (unsigned char)(__builtin_amdgcn_cvt_pk_fp8_f32(x, 0.f, 0, false) & 0xFF);
}

// accumulate 16 fp8 (one uint4) scaled by v into 8 packed-f32 accumulators
__device__ __forceinline__ void acc16(f32x2* a, uint4 q, float v) {
  f32x2 vv = {v, v};
  a[0] += vv * __builtin_amdgcn_cvt_pk_f32_fp8(q.x, false);
  a[1] += vv * __builtin_amdgcn_cvt_pk_f32_fp8(q.x, true);
  a[2] += vv * __builtin_amdgcn_cvt_pk_f32_fp8(q.y, false);
  a[3] += vv * __builtin_amdgcn_cvt_pk_f32_fp8(q.y, true);
  a[4] += vv * __builtin_amdgcn_cvt_pk_f32_fp8(q.z, false);
  a[5] += vv * __builtin_amdgcn_cvt_pk_f32_fp8(q.z, true);
  a[6] += vv * __builtin_amdgcn_cvt_pk_f32_fp8(q.w, false);
  a[7] += vv * __builtin_amdgcn_cvt_pk_f32_fp8(q.w, true);
}

// gather one row's features: RS uint4 per source row, lane owns chunk f.
// 4-deep gathers + meta prefetched one batch ahead (R17; R19's 8-deep
// regressed). Accumulation order identical to sequential-j.
template <int RS>
__device__ __forceinline__ void gather_row(
    const int2* __restrict__ sedge, const uint4* __restrict__ Hq,
    int beg, int end, int f, f32x2* a) {
  int j = beg;
  if ((j & 1) && j < end) {  // peel to 16B-align the meta stream
    int2 ev = sedge[j];
    acc16(a, Hq[ev.x * RS + f], __int_as_float(ev.y));
    ++j;
  }
  if (j + 4 <= end) {
    const int4* mp = (const int4*)sedge;
    int4 m0 = mp[j >> 1], m1 = mp[(j >> 1) + 1];
    while (j + 8 <= end) {
      uint4 q0 = Hq[m0.x * RS + f];
      uint4 q1 = Hq[m0.z * RS + f];
      uint4 q2 = Hq[m1.x * RS + f];
      uint4 q3 = Hq[m1.z * RS + f];
      int4 n0 = mp[(j >> 1) + 2];   // prefetch next batch's meta
      int4 n1 = mp[(j >> 1) + 3];
      acc16(a, q0, __int_as_float(m0.y));
      acc16(a, q1, __int_as_float(m0.w));
      acc16(a, q2, __int_as_float(m1.y));
      acc16(a, q3, __int_as_float(m1.w));
      m0 = n0;
      m1 = n1;
      j += 4;
    }
    // final full batch (meta already in registers)
    uint4 q0 = Hq[m0.x * RS + f];
    uint4 q1 = Hq[m0.z * RS + f];
    uint4 q2 = Hq[m1.x * RS + f];
    uint4 q3 = Hq[m1.z * RS + f];
    acc16(a, q0, __int_as_float(m0.y));
    acc16(a, q1, __int_as_float(m0.w));
    acc16(a, q2, __int_as_float(m1.y));
    acc16(a, q3, __int_as_float(m1.w));
    j += 4;
  }
  for (; j < end; ++j) {
    int2 ev = sedge[j];
    acc16(a, Hq[ev.x * RS + f], __int_as_float(ev.y));
  }
}

// ---------------- fused prep: H->fp8, W1/W2 -> swizzled bf16 ----------------
__global__ __launch_bounds__(256) void prep_kernel(
    const float* __restrict__ H, const float* __restrict__ W1,
    const float* __restrict__ W2, unsigned char* __restrict__ Hf8,
    unsigned short* __restrict__ Wsw1, unsigned short* __restrict__ Wsw2,
    int n8) {
  const int total = n8 + 64 * 128 + 128 * 128;
  for (int w = blockIdx.x * 256 + threadIdx.x; w < total; w += gridDim.x * 256) {
    if (w < n8) {
      float4 a = ((const float4*)H)[2 * w];
      float4 b = ((const float4*)H)[2 * w + 1];
      ((uint2*)Hf8)[w] = make_uint2(pk_fp8x4(a.x, a.y, a.z, a.w),
                                    pk_fp8x4(b.x, b.y, b.z, b.w));
    } else {
      int idx = w - n8;
      const float* W = W1;
      unsigned short* Wsw = Wsw1;
      if (idx >= 64 * 128) {
        idx -= 64 * 128;
        W = W2;
        Wsw = Wsw2;
      }
      int j = idx & 7, q = (idx >> 3) & 3, nn = (idx >> 5) & 127, kt = idx >> 12;
      int k = kt * 32 + q * 8 + j;
      Wsw[idx] = f2bf(W[(size_t)k * 128 + nn]);
    }
  }
}

// ---------------- bucket histogram (LDS-aggregated, int4 reads) ------------
__global__ __launch_bounds__(256) void bhist_kernel(
    const int* __restrict__ row, int* __restrict__ bcnt, int n_edges, int nb) {
  __shared__ int h[NB_MAX];
  for (int i = threadIdx.x; i < NB_MAX; i += 256) h[i] = 0;
  __syncthreads();
  const int n4 = n_edges >> 2;
  for (int i = blockIdx.x * 256 + threadIdx.x; i < n4; i += gridDim.x * 256) {
    int4 r4 = ((const int4*)row)[i];
    atomicAdd(&h[r4.x >> BSHIFT], 1);
    atomicAdd(&h[r4.y >> BSHIFT], 1);
    atomicAdd(&h[r4.z >> BSHIFT], 1);
    atomicAdd(&h[r4.w >> BSHIFT], 1);
  }
  if (blockIdx.x == 0 && threadIdx.x < (n_edges & 3))
    atomicAdd(&h[row[(n4 << 2) + threadIdx.x] >> BSHIFT], 1);
  __syncthreads();
  for (int i = threadIdx.x; i < nb; i += 256)
    if (h[i]) atomicAdd(&bcnt[i], h[i]);
}

// ---------------- bucket scan -> bbase[nb+1], cur[nb], row_ptr[n] -----------
__global__ __launch_bounds__(NB_MAX) void bscan_kernel(
    const int* __restrict__ bcnt, int* __restrict__ bbase, int* __restrict__ cur,
    int* __restrict__ row_ptr, int nb, int n) {
  __shared__ int sm[NB_MAX];
  int t = threadIdx.x;
  int v = (t < nb) ? bcnt[t] : 0;
  sm[t] = v;
  __syncthreads();
  for (int off = 1; off < NB_MAX; off <<= 1) {
    int u = (t >= off) ? sm[t - off] : 0;
    __syncthreads();
    sm[t] += u;
    __syncthreads();
  }
  if (t < nb) {
    bbase[t] = sm[t] - v;
    cur[t] = sm[t] - v;
  }
  if (t == nb - 1) {
    bbase[nb] = sm[t];
    row_ptr[n] = sm[t];
  }
}

// ---------------- pass A: multi-split partition into buckets ----------------
// 256 blocks (256B per-bucket chunks for write coalescing) x 1024 threads
// (16 waves/CU). Both edge passes int4/float4-vectorized.
__global__ __launch_bounds__(1024) void partition_kernel(
    const int* __restrict__ row, const int* __restrict__ col,
    const float* __restrict__ vals, int* __restrict__ cur,
    int2* __restrict__ bedge, int n_edges) {
  __shared__ int h[NB_MAX], base[NB_MAX], rk[NB_MAX];
  for (int i = threadIdx.x; i < NB_MAX; i += 1024) {
    h[i] = 0;
    rk[i] = 0;
  }
  __syncthreads();
  const int t0 = blockIdx.x * 1024 + threadIdx.x;
  const int T = gridDim.x * 1024;
  const int n4 = n_edges >> 2;
  for (int i = t0; i < n4; i += T) {
    int4 r4 = ((const int4*)row)[i];
    atomicAdd(&h[r4.x >> BSHIFT], 1);
    atomicAdd(&h[r4.y >> BSHIFT], 1);
    atomicAdd(&h[r4.z >> BSHIFT], 1);
    atomicAdd(&h[r4.w >> BSHIFT], 1);
  }
  if (blockIdx.x == 0 && threadIdx.x < (n_edges & 3))
    atomicAdd(&h[row[(n4 << 2) + threadIdx.x] >> BSHIFT], 1);
  __syncthreads();
  for (int i = threadIdx.x; i < NB_MAX; i += 1024)
    base[i] = h[i] ? atomicAdd(&cur[i], h[i]) : 0;
  __syncthreads();
  for (int i = t0; i < n4; i += T) {
    int4 r4 = ((const int4*)row)[i];
    int4 c4 = ((const int4*)col)[i];
    float4 v4 = ((const float4*)vals)[i];
    {
      int b = r4.x >> BSHIFT;
      int p = base[b] + atomicAdd(&rk[b], 1);
      bedge[p] = make_int2(((r4.x & (BROWS - 1)) << 17) | c4.x, __float_as_int(v4.x));
    }
    {
      int b = r4.y >> BSHIFT;
      int p = base[b] + atomicAdd(&rk[b], 1);
      bedge[p] = make_int2(((r4.y & (BROWS - 1)) << 17) | c4.y, __float_as_int(v4.y));
    }
    {
      int b = r4.z >> BSHIFT;
      int p = base[b] + atomicAdd(&rk[b], 1);
      bedge[p] = make_int2(((r4.z & (BROWS - 1)) << 17) | c4.z, __float_as_int(v4.z));
    }
    {
      int b = r4.w >> BSHIFT;
      int p = base[b] + atomicAdd(&rk[b], 1);
      bedge[p] = make_int2(((r4.w & (BROWS - 1)) << 17) | c4.w, __float_as_int(v4.w));
    }
  }
  if (blockIdx.x == 0 && threadIdx.x < (n_edges & 3)) {
    int e = (n4 << 2) + threadIdx.x;
    int r = row[e];
    int b = r >> BSHIFT;
    int p = base[b] + atomicAdd(&rk[b], 1);
    bedge[p] = make_int2(((r & (BROWS - 1)) << 17) | col[e], __float_as_int(vals[e]));
  }
}

// ---------------- pass B: per-bucket exact CSR (1024 thr) ----------------
__global__ __launch_bounds__(1024) void bucket_csr_kernel(
    const int* __restrict__ bbase, const int2* __restrict__ bedge,
    int* __restrict__ row_ptr, int2* __restrict__ sedge, int n) {
  __shared__ int cnt[BROWS];
  __shared__ int sm[BROWS];
  const int b = blockIdx.x;
  const int t = threadIdx.x;
  const int beg = bbase[b], end = bbase[b + 1];
  if (t < BROWS) cnt[t] = 0;
  __syncthreads();
  for (int j = beg + t; j < end; j += 1024)
    atomicAdd(&cnt[((unsigned)bedge[j].x) >> 17], 1);
  __syncthreads();
  int v = (t < BROWS) ? cnt[t] : 0;
  if (t < BROWS) sm[t] = v;
  __syncthreads();
  for (int off = 1; off < BROWS; off <<= 1) {
    int u = (t >= off && t < BROWS) ? sm[t - off] : 0;
    __syncthreads();
    if (t < BROWS) sm[t] += u;
    __syncthreads();
  }
  int incl = (t < BROWS) ? sm[t] : 0;
  __syncthreads();
  if (t < BROWS) {
    sm[t] = incl - v;  // exclusive local base
    int r = (b << BSHIFT) + t;
    if (r < n) row_ptr[r] = beg + sm[t];
    cnt[t] = 0;
  }
  __syncthreads();
  for (int j = beg + t; j < end; j += 1024) {
    int2 ev = bedge[j];
    int rl = ((unsigned)ev.x) >> 17;
    int rank = atomicAdd(&cnt[rl], 1);
    sedge[beg + sm[rl] + rank] = make_int2(ev.x & 0x1FFFF, ev.y);
  }
}

// ---------------- fused layer 1: H1f8 = fp8(relu((A@Hf8) @ W1 + b1)) -------
// R20: 128 thr, 32 rows/block. Phase 1: 4 lanes/row gather 64-feat fp8 ->
// LDS tile [32][144B]. Phase 2: 2 waves x 16 rows MFMA vs Wsw1 (all cols).
__global__ __launch_bounds__(128) void fused64_kernel(
    const int* __restrict__ row_ptr, const int2* __restrict__ sedge,
    const unsigned char* __restrict__ Hf8,
    const unsigned short* __restrict__ Wsw,
    const float* __restrict__ b, unsigned char* __restrict__ H1f8, int n) {
  __shared__ uint4 tile[32 * 9];  // stride 9 uint4 = 144B
  const int tid = threadIdx.x;
  {
    const int rl = tid >> 2, f = tid & 3;  // 32 rows x 4 lanes
    const int r = blockIdx.x * 32 + rl;
    int beg = 0, end = 0;
    if (r < n) {
      beg = row_ptr[r];
      end = row_ptr[r + 1];
    }
    f32x2 a[8];
#pragma unroll
    for (int i = 0; i < 8; ++i) a[i] = (f32x2){0.f, 0.f};
    gather_row<4>(sedge, (const uint4*)Hf8, beg, end, f, a);
    tile[rl * 9 + f * 2] =
        make_uint4(pack2(a[0].x, a[0].y), pack2(a[1].x, a[1].y),
                   pack2(a[2].x, a[2].y), pack2(a[3].x, a[3].y));
    tile[rl * 9 + f * 2 + 1] =
        make_uint4(pack2(a[4].x, a[4].y), pack2(a[5].x, a[5].y),
                   pack2(a[6].x, a[6].y), pack2(a[7].x, a[7].y));
  }
  const int lane = tid & 63, wave = tid >> 6;  // 2 waves
  const int m = lane & 15, quad = lane >> 4;
  bf16x8 bfr[2][8];
#pragma unroll
  for (int kt = 0; kt < 2; ++kt)
#pragma unroll
    for (int c = 0; c < 8; ++c)
      bfr[kt][c] = *(const bf16x8*)(Wsw + ((size_t)(kt * 128 + c * 16 + m)) * 32 + quad * 8);
  __syncthreads();
  f32x4 acc[8];
#pragma unroll
  for (int c = 0; c < 8; ++c) acc[c] = (f32x4){0.f, 0.f, 0.f, 0.f};
#pragma unroll
  for (int kt = 0; kt < 2; ++kt) {
    bf16x8 a = *(const bf16x8*)&tile[(wave * 16 + m) * 9 + kt * 4 + quad];
#pragma unroll
    for (int c = 0; c < 8; ++c)
      acc[c] = __builtin_amdgcn_mfma_f32_16x16x32_bf16(a, bfr[kt][c], acc[c], 0, 0, 0);
  }
  const int r0 = blockIdx.x * 32 + wave * 16;
#pragma unroll
  for (int c = 0; c < 8; ++c) {
    float bias = b[c * 16 + m];
#pragma unroll
    for (int i = 0; i < 4; ++i) {
      int rr = r0 + quad * 4 + i;
      if (rr >= n) continue;
      H1f8[(size_t)rr * 128 + c * 16 + m] = f2fp8(fmaxf(acc[c][i] + bias, 0.f));
    }
  }
}

// ---------------- fused layer 2: out = relu((A@H1f8) @ W2 + b2) ------------
// R20: 128 thr, 16 rows/block. Phase 1: 8 lanes/row gather 128-feat fp8 ->
// LDS tile [16][272B]. Phase 2: 2 waves = 1 row-group x 2 col-halves.
__global__ __launch_bounds__(128) void fused128_kernel(
    const int* __restrict__ row_ptr, const int2* __restrict__ sedge,
    const unsigned char* __restrict__ H1f8,
    const unsigned short* __restrict__ Wsw,
    const float* __restrict__ b, float* __restrict__ out, int n) {
  __shared__ uint4 tile[16 * 17];  // stride 17 uint4 = 272B
  const int tid = threadIdx.x;
  {
    const int rl = tid >> 3, f = tid & 7;  // 16 rows x 8 lanes
    const int r = blockIdx.x * 16 + rl;
    int beg = 0, end = 0;
    if (r < n) {
      beg = row_ptr[r];
      end = row_ptr[r + 1];
    }
    f32x2 a[8];
#pragma unroll
    for (int i = 0; i < 8; ++i) a[i] = (f32x2){0.f, 0.f};
    gather_row<8>(sedge, (const uint4*)H1f8, beg, end, f, a);
    tile[rl * 17 + f * 2] =
        make_uint4(pack2(a[0].x, a[0].y), pack2(a[1].x, a[1].y),
                   pack2(a[2].x, a[2].y), pack2(a[3].x, a[3].y));
    tile[rl * 17 + f * 2 + 1] =
        make_uint4(pack2(a[4].x, a[4].y), pack2(a[5].x, a[5].y),
                   pack2(a[6].x, a[6].y), pack2(a[7].x, a[7].y));
  }
  const int lane = tid & 63, wave = tid >> 6;
  const int m = lane & 15, quad = lane >> 4;
  const int h = wave;  // col half (64)
  bf16x8 bfr[4][4];
#pragma unroll
  for (int kt = 0; kt < 4; ++kt)
#pragma unroll
    for (int c = 0; c < 4; ++c)
      bfr[kt][c] = *(const bf16x8*)(Wsw + ((size_t)(kt * 128 + (h * 4 + c) * 16 + m)) * 32 + quad * 8);
  __syncthreads();
  f32x4 acc[4];
#pragma unroll
  for (int c = 0; c < 4; ++c) acc[c] = (f32x4){0.f, 0.f, 0.f, 0.f};
#pragma unroll
  for (int kt = 0; kt < 4; ++kt) {
    bf16x8 a = *(const bf16x8*)&tile[m * 17 + kt * 4 + quad];
#pragma unroll
    for (int c = 0; c < 4; ++c)
      acc[c] = __builtin_amdgcn_mfma_f32_16x16x32_bf16(a, bfr[kt][c], acc[c], 0, 0, 0);
  }
  const int r0 = blockIdx.x * 16;
#pragma unroll
  for (int c = 0; c < 4; ++c) {
    float bias = b[(h * 4 + c) * 16 + m];
#pragma unroll
    for (int i = 0; i < 4; ++i) {
      int rr = r0 + quad * 4 + i;
      if (rr >= n) continue;
      out[(size_t)rr * 128 + (h * 4 + c) * 16 + m] = fmaxf(acc[c][i] + bias, 0.f);
    }
  }
}

// ---------------- fallback path (f32 atomics + f32 VALU GEMM) ----------------
__global__ __launch_bounds__(256) void spmm64_atomic(
    const int* __restrict__ row, const int* __restrict__ col,
    const float* __restrict__ vals, const float* __restrict__ Hin,
    float* __restrict__ out, int n_edges) {
  int tid = blockIdx.x * 256 + threadIdx.x;
  int e = tid >> 4, f = tid & 15;
  if (e >= n_edges) return;
  int c = col[e], r = row[e];
  float v = vals[e];
  float4 h = ((const float4*)Hin)[(size_t)c * 16 + f];
  float* o = out + (size_t)r * 64 + f * 4;
  atomicAdd(o + 0, v * h.x);
  atomicAdd(o + 1, v * h.y);
  atomicAdd(o + 2, v * h.z);
  atomicAdd(o + 3, v * h.w);
}

__global__ __launch_bounds__(256) void spmm128_atomic(
    const int* __restrict__ row, const int* __restrict__ col,
    const float* __restrict__ vals, const float* __restrict__ Hin,
    float* __restrict__ out, int n_edges) {
  int tid = blockIdx.x * 256 + threadIdx.x;
  int e = tid >> 5, f = tid & 31;
  if (e >= n_edges) return;
  int c = col[e], r = row[e];
  float v = vals[e];
  float4 h = ((const float4*)Hin)[(size_t)c * 32 + f];
  float* o = out + (size_t)r * 128 + f * 4;
  atomicAdd(o + 0, v * h.x);
  atomicAdd(o + 1, v * h.y);
  atomicAdd(o + 2, v * h.z);
  atomicAdd(o + 3, v * h.w);
}

template <int K>
__global__ __launch_bounds__(256) void gemm_tiled_relu(
    const float* __restrict__ A, const float* __restrict__ W,
    const float* __restrict__ b, float* __restrict__ out, int n) {
  constexpr int KB = 32;
  constexpr int RP = 132;
  __shared__ float As[KB][RP];
  __shared__ float Ws[KB][128];
  const int t = threadIdx.x;
  const int tx = t & 15, ty = t >> 4;
  const int r0 = blockIdx.x * 128;
  float4 acc0[8], acc1[8];
#pragma unroll
  for (int i = 0; i < 8; ++i) {
    acc0[i] = make_float4(0.f, 0.f, 0.f, 0.f);
    acc1[i] = make_float4(0.f, 0.f, 0.f, 0.f);
  }
  for (int k0 = 0; k0 < K; k0 += KB) {
#pragma unroll
    for (int q = 0; q < 4; ++q) {
      int f = q * 256 + t;
      int kk = f >> 5, cv = f & 31;
      ((float4*)&Ws[kk][0])[cv] = ((const float4*)(W + (size_t)(k0 + kk) * 128))[cv];
    }
#pragma unroll
    for (int q = 0; q < 4; ++q) {
      int f = q * 256 + t;
      int r = f >> 3, kv = f & 7;
      float4 av = make_float4(0.f, 0.f, 0.f, 0.f);
      if (r0 + r < n) av = ((const float4*)(A + (size_t)(r0 + r) * K + k0))[kv];
      As[4 * kv + 0][r] = av.x;
      As[4 * kv + 1][r] = av.y;
      As[4 * kv + 2][r] = av.z;
      As[4 * kv + 3][r] = av.w;
    }
    __syncthreads();
#pragma unroll
    for (int k = 0; k < KB; ++k) {
      float4 w0 = *((const float4*)&Ws[k][4 * tx]);
      float4 w1 = *((const float4*)&Ws[k][64 + 4 * tx]);
#pragma unroll
      for (int i = 0; i < 8; ++i) {
        float a = As[k][ty + 16 * i];
        acc0[i].x = fmaf(a, w0.x, acc0[i].x);
        acc0[i].y = fmaf(a, w0.y, acc0[i].y);
        acc0[i].z = fmaf(a, w0.z, acc0[i].z);
        acc0[i].w = fmaf(a, w0.w, acc0[i].w);
        acc1[i].x = fmaf(a, w1.x, acc1[i].x);
        acc1[i].y = fmaf(a, w1.y, acc1[i].y);
        acc1[i].z = fmaf(a, w1.z, acc1[i].z);
        acc1[i].w = fmaf(a, w1.w, acc1[i].w);
      }
    }
    __syncthreads();
  }
  float4 bb0 = ((const float4*)b)[tx];
  float4 bb1 = ((const float4*)(b + 64))[tx];
#pragma unroll
  for (int i = 0; i < 8; ++i) {
    int r = r0 + ty + 16 * i;
    if (r >= n) continue;
    float4 o0, o1;
    o0.x = fmaxf(acc0[i].x + bb0.x, 0.f);
    o0.y = fmaxf(acc0[i].y + bb0.y, 0.f);
    o0.z = fmaxf(acc0[i].z + bb0.z, 0.f);
    o0.w = fmaxf(acc0[i].w + bb0.w, 0.f);
    o1.x = fmaxf(acc1[i].x + bb1.x, 0.f);
    o1.y = fmaxf(acc1[i].y + bb1.y, 0.f);
    o1.z = fmaxf(acc1[i].z + bb1.z, 0.f);
    o1.w = fmaxf(acc1[i].w + bb1.w, 0.f);
    ((float4*)(out + (size_t)r * 128))[tx] = o0;
    ((float4*)(out + (size_t)r * 128 + 64))[tx] = o1;
  }
}

extern "C" void kernel_launch(void* const* d_in, const int* in_sizes, int n_in,
                              void* d_out, int out_size, void* d_ws, size_t ws_size,
                              hipStream_t stream) {
  const int* row = (const int*)d_in[0];
  const int* col = (const int*)d_in[1];
  const float* vals = (const float*)d_in[2];
  const float* H = (const float*)d_in[3];
  const float* W1 = (const float*)d_in[4];
  const float* b1 = (const float*)d_in[5];
  const float* W2 = (const float*)d_in[6];
  const float* b2 = (const float*)d_in[7];
  float* out = (float*)d_out;

  const int n_edges = in_sizes[0];
  const int n_nodes = in_sizes[3] / NFEAT;
  const int nb = (n_nodes + BROWS - 1) / BROWS;

  // Workspace layout (CSR path):
  // bedge E*8 | Hf8 N*64 | H1f8 N*128 | sedge E*8
  // | Wsw1 | Wsw2 | bcnt | bbase | cur | row_ptr
  size_t off = 0;
  char* base = (char*)d_ws;
  int2* bedge = (int2*)(base + off);  off += (size_t)n_edges * 8;
  unsigned char* Hf8 = (unsigned char*)(base + off);   off += (size_t)n_nodes * NFEAT;
  unsigned char* H1f8 = (unsigned char*)(base + off);  off += (size_t)n_nodes * NHID;
  int2* sedge = (int2*)(base + off);  off += (size_t)n_edges * 8;
  unsigned short* Wsw1 = (unsigned short*)(base + off); off += 64 * 128 * 2;
  unsigned short* Wsw2 = (unsigned short*)(base + off); off += 128 * 128 * 2;
  int* bcnt = (int*)(base + off);     off += NB_MAX * 4;
  int* bbase = (int*)(base + off);    off += (NB_MAX + 1) * 4;
  int* cur = (int*)(base + off);      off += NB_MAX * 4;
  int* row_ptr = (int*)(base + off);  off += ((size_t)n_nodes + 1) * 4;
  const size_t needed = off;

  if (ws_size >= needed && nb <= NB_MAX && n_nodes <= (1 << 17)) {
    // ---- bucket-sort CSR build ----
    hipMemsetAsync(bcnt, 0, NB_MAX * sizeof(int), stream);
    bhist_kernel<<<1024, 256, 0, stream>>>(row, bcnt, n_edges, nb);
    bscan_kernel<<<1, NB_MAX, 0, stream>>>(bcnt, bbase, cur, row_ptr, nb, n_nodes);
    partition_kernel<<<256, 1024, 0, stream>>>(row, col, vals, cur, bedge, n_edges);
    bucket_csr_kernel<<<nb, 1024, 0, stream>>>(bbase, bedge, row_ptr, sedge, n_nodes);

    // Fused prep: H -> fp8, W1/W2 -> swizzled bf16.
    prep_kernel<<<1024, 256, 0, stream>>>(H, W1, W2, Hf8, Wsw1, Wsw2,
                                          n_nodes * NFEAT / 8);

    // Layer 1 fused: H1f8 = fp8(relu((A@Hf8) @ W1 + b1))
    fused64_kernel<<<(n_nodes + 31) / 32, 128, 0, stream>>>(
        row_ptr, sedge, Hf8, Wsw1, b1, H1f8, n_nodes);
    // Layer 2 fused: out = relu((A@H1f8) @ W2 + b2)
    fused128_kernel<<<(n_nodes + 15) / 16, 128, 0, stream>>>(
        row_ptr, sedge, H1f8, Wsw2, b2, out, n_nodes);
  } else {
    // ---- fallback: atomic scatter path (all f32) ----
    float* fAH = (float*)d_ws;
    float* fH1 = fAH + (size_t)n_nodes * NFEAT;
    hipMemsetAsync(fAH, 0, (size_t)n_nodes * NFEAT * sizeof(float), stream);
    hipMemsetAsync(out, 0, (size_t)n_nodes * NHID * sizeof(float), stream);
    spmm64_atomic<<<(n_edges * 16 + 255) / 256, 256, 0, stream>>>(row, col, vals, H, fAH, n_edges);
    gemm_tiled_relu<64><<<(n_nodes + 127) / 128, 256, 0, stream>>>(fAH, W1, b1, fH1, n_nodes);
    spmm128_atomic<<<(n_edges * 32 + 255) / 256, 256, 0, stream>>>(row, col, vals, fH1, out, n_edges);
    gemm_tiled_relu<128><<<(n_nodes + 127) / 128, 256, 0, stream>>>(out, W2, b2, out, n_nodes);
  }
}